// Round 1
// baseline (374.919 us; speedup 1.0000x reference)
//
#include <hip/hip_runtime.h>
#include <stdint.h>

#define IN_DIM 512
#define NT 64
#define AH 128
#define NCLS 10
#define BN_EPS_C 1e-5f
#define SHRINK 0.3f

typedef __bf16 bf16x8 __attribute__((ext_vector_type(8)));
typedef float f32x4 __attribute__((ext_vector_type(4)));
typedef unsigned int u32x4 __attribute__((ext_vector_type(4)));

__device__ __forceinline__ unsigned short f2bf(float f) {
  unsigned u = __builtin_bit_cast(unsigned, f);
  u += 0x7fffu + ((u >> 16) & 1u);   // RNE; inputs are NaN-free by construction
  return (unsigned short)(u >> 16);
}

__device__ __forceinline__ void gload_lds16(const void* g, void* l) {
  __builtin_amdgcn_global_load_lds(
      (const __attribute__((address_space(1))) void*)g,
      (__attribute__((address_space(3))) void*)l, 16, 0, 0);
}

// read one 16B MFMA fragment from a swizzled [rows][64] bf16 LDS tile
__device__ __forceinline__ bf16x8 frag_ld(const char* lds, int r, int q) {
  return *reinterpret_cast<const bf16x8*>(lds + r * 128 + ((q ^ (r & 7)) * 16));
}

// ---------------- converters ----------------

// x[16384][512] fp32 -> xc bf16 (NaN->0) + per-row missing flag
__global__ void k_convert_x(const float* __restrict__ x, unsigned short* __restrict__ xc,
                            float* __restrict__ flags) {
  int wid = threadIdx.x >> 6, lane = threadIdx.x & 63;
  int row = blockIdx.x * 4 + wid;
  const float* px = x + row * IN_DIM + lane * 8;
  float4 a = *(const float4*)px;
  float4 b = *(const float4*)(px + 4);
  float v[8] = {a.x, a.y, a.z, a.w, b.x, b.y, b.z, b.w};
  bool nan_any = false;
  union { unsigned short s[8]; u32x4 u; } pk;
#pragma unroll
  for (int i = 0; i < 8; i++) {
    bool n = (v[i] != v[i]);
    nan_any |= n;
    pk.s[i] = f2bf(n ? 0.f : v[i]);
  }
  *reinterpret_cast<u32x4*>(xc + row * IN_DIM + lane * 8) = pk.u;
  unsigned long long bal = __ballot(nan_any);
  if (lane == 0) flags[row] = bal ? 1.f : 0.f;
}

// tree_w [64][63][512] fp32 -> [64][64][512] bf16 (node 63 zero-padded)
__global__ void k_convert_tw(const float* __restrict__ tw, unsigned short* __restrict__ twb) {
  int tid = blockIdx.x * 256 + threadIdx.x;  // 262144 threads
  int o = tid * 8;
  int k = o & 511;
  int nt = o >> 9;
  int node = nt & 63, t = nt >> 6;
  union { unsigned short s[8]; u32x4 u; } pk;
  if (node < 63) {
    const float* p = tw + ((t * 63 + node) * 512 + k);
    float4 a = *(const float4*)p, b = *(const float4*)(p + 4);
    float v[8] = {a.x, a.y, a.z, a.w, b.x, b.y, b.z, b.w};
#pragma unroll
    for (int i = 0; i < 8; i++) pk.s[i] = f2bf(v[i]);
  } else {
#pragma unroll
    for (int i = 0; i < 8; i++) pk.s[i] = 0;
  }
  *reinterpret_cast<u32x4*>(twb + o) = pk.u;
}

// w1 [512][128] fp32 -> w1t [128][512] bf16 (transposed)
__global__ void k_convert_w1t(const float* __restrict__ w1, unsigned short* __restrict__ w1t) {
  int tid = blockIdx.x * 256 + threadIdx.x;  // 65536
  int k = tid & 511, n = tid >> 9;
  w1t[n * 512 + k] = f2bf(w1[k * 128 + n]);
}

// ---------------- attention ----------------

// h = BN(relu(x@w1 + b1)) : M=16384 N=128 K=512, tile 64x128
__global__ void __launch_bounds__(256) k_attn1(
    const unsigned short* __restrict__ xc, const unsigned short* __restrict__ w1t,
    const float* __restrict__ b1, const float* __restrict__ gam,
    const float* __restrict__ bet, const float* __restrict__ mu,
    const float* __restrict__ var, float* __restrict__ h) {
  __shared__ __align__(16) char smem[24576];
  char* As = smem;          // 64x64 bf16 = 8192
  char* Bs = smem + 8192;   // 128x64 bf16 = 16384
  int lane = threadIdx.x & 63, wid = threadIdx.x >> 6;
  int bm0 = blockIdx.x * 64;
  int m = lane & 15, q = lane >> 4;
  int sub = lane >> 3, cpos = lane & 7;
  f32x4 acc[8];
#pragma unroll
  for (int j = 0; j < 8; j++) acc[j] = f32x4{0.f, 0.f, 0.f, 0.f};
  const unsigned short* Ag = xc + (size_t)bm0 * 512;

  for (int ko = 0; ko < 8; ++ko) {
    const unsigned short* Ak = Ag + ko * 64;
    const unsigned short* Bk = w1t + ko * 64;
#pragma unroll
    for (int i = 0; i < 2; i++) {
      int seg = wid * 2 + i;
      int r = seg * 8 + sub;
      int cg = cpos ^ (r & 7);
      gload_lds16(Ak + r * 512 + cg * 8, As + seg * 1024);
    }
#pragma unroll
    for (int i = 0; i < 4; i++) {
      int seg = wid * 4 + i;
      int r = seg * 8 + sub;
      int cg = cpos ^ (r & 7);
      gload_lds16(Bk + r * 512 + cg * 8, Bs + seg * 1024);
    }
    __syncthreads();
#pragma unroll
    for (int ks = 0; ks < 2; ++ks) {
      bf16x8 af = frag_ld(As, wid * 16 + m, ks * 4 + q);
#pragma unroll
      for (int ni = 0; ni < 8; ni++) {
        bf16x8 bfr = frag_ld(Bs, ni * 16 + m, ks * 4 + q);
        acc[ni] = __builtin_amdgcn_mfma_f32_16x16x32_bf16(af, bfr, acc[ni], 0, 0, 0);
      }
    }
    __syncthreads();
  }
#pragma unroll
  for (int ni = 0; ni < 8; ni++) {
    int col = ni * 16 + m;
    float bb = b1[col], ga = gam[col], be = bet[col], mm = mu[col];
    float iv = rsqrtf(var[col] + BN_EPS_C);
#pragma unroll
    for (int r4 = 0; r4 < 4; r4++) {
      int row = bm0 + wid * 16 + q * 4 + r4;
      float v = acc[ni][r4] + bb;
      v = fmaxf(v, 0.f);
      v = (v - mm) * iv * ga + be;
      h[row * AH + col] = v;
    }
  }
}

// attn = softmax(h@w2 + b2); wbt = attn * SHRINK * rw
__global__ void __launch_bounds__(256) k_attn2(
    const float* __restrict__ h, const float* __restrict__ w2,
    const float* __restrict__ b2, const float* __restrict__ rw,
    float* __restrict__ wbt) {
  __shared__ float w2s[AH * NT];
  __shared__ float hs[4][AH];
  int lane = threadIdx.x & 63, wid = threadIdx.x >> 6;
  for (int i = threadIdx.x; i < AH * NT; i += 256) w2s[i] = w2[i];
  __syncthreads();
  float bb = b2[lane];
  float cf = SHRINK * rw[lane];
  for (int rr = 0; rr < 4; ++rr) {
    int row = blockIdx.x * 16 + wid * 4 + rr;
    float2 hv = *(const float2*)(h + row * AH + lane * 2);
    hs[wid][lane * 2] = hv.x;
    hs[wid][lane * 2 + 1] = hv.y;
    __syncthreads();
    float s = bb;
#pragma unroll 8
    for (int k = 0; k < AH; k++) s = fmaf(hs[wid][k], w2s[k * NT + lane], s);
    float mx = s;
#pragma unroll
    for (int o = 1; o < 64; o <<= 1) mx = fmaxf(mx, __shfl_xor(mx, o));
    float e = __expf(s - mx);
    float sm = e;
#pragma unroll
    for (int o = 1; o < 64; o <<= 1) sm += __shfl_xor(sm, o);
    wbt[row * NT + lane] = (e / sm) * cf;
    __syncthreads();
  }
}

// ---------------- main: tree logits + routing + leaf + pred accumulate ----------------
// tile: 128 rows x 128 cols (2 trees x 64 padded nodes), BK=64, 4 waves
__global__ void __launch_bounds__(256) k_trees(
    const unsigned short* __restrict__ xc,   // [16384][512]
    const unsigned short* __restrict__ twb,  // [64*64][512]
    const float* __restrict__ tree_b,        // [64][63]
    const float* __restrict__ tree_temp,     // [64]
    const float* __restrict__ leaf,          // [64][64][10]
    const float* __restrict__ wbt,           // [16384][64]
    const float* __restrict__ flags,         // [16384]
    float* __restrict__ pred) {              // [16384][10]
  __shared__ __align__(16) char smem[40960];
  char* As = smem;           // 128x64 bf16 = 16384
  char* Bs = smem + 16384;   // 128x64 bf16 = 16384
  int lane = threadIdx.x & 63, wid = threadIdx.x >> 6;
  int bm0 = blockIdx.x * 128;
  int t0 = blockIdx.y * 2;   // 2 trees per block
  int m = lane & 15, q = lane >> 4;
  int sub = lane >> 3, cpos = lane & 7;

  f32x4 acc[2][8];
#pragma unroll
  for (int i = 0; i < 2; i++)
#pragma unroll
    for (int j = 0; j < 8; j++) acc[i][j] = f32x4{0.f, 0.f, 0.f, 0.f};

  const unsigned short* Ag = xc + (size_t)bm0 * 512;
  const unsigned short* Bg = twb + (size_t)t0 * 64 * 512;
  int rA0 = wid * 32 + m;

  for (int ko = 0; ko < 8; ++ko) {
    const unsigned short* Ak = Ag + ko * 64;
    const unsigned short* Bk = Bg + ko * 64;
#pragma unroll
    for (int i = 0; i < 4; i++) {
      int seg = wid * 4 + i;
      int r = seg * 8 + sub;
      int cg = cpos ^ (r & 7);
      gload_lds16(Ak + r * 512 + cg * 8, As + seg * 1024);
      gload_lds16(Bk + r * 512 + cg * 8, Bs + seg * 1024);
    }
    __syncthreads();
#pragma unroll
    for (int ks = 0; ks < 2; ++ks) {
      bf16x8 af[2];
#pragma unroll
      for (int mi = 0; mi < 2; mi++) af[mi] = frag_ld(As, rA0 + mi * 16, ks * 4 + q);
#pragma unroll
      for (int ni = 0; ni < 8; ni++) {
        bf16x8 bfr = frag_ld(Bs, ni * 16 + m, ks * 4 + q);
#pragma unroll
        for (int mi = 0; mi < 2; mi++)
          acc[mi][ni] = __builtin_amdgcn_mfma_f32_16x16x32_bf16(af[mi], bfr, acc[mi][ni], 0, 0, 0);
      }
    }
    __syncthreads();
  }

  // ---- epilogue: reuse LDS for dec (per-wave 32x66 f32) + leaf values ----
  float* decw = reinterpret_cast<float*>(smem) + wid * (32 * 66);     // 33792 B
  float* leaf_s = reinterpret_cast<float*>(smem) + 4 * 32 * 66;       // 1280 f32
  for (int i = threadIdx.x; i < 2 * 640; i += 256) leaf_s[i] = leaf[t0 * 640 + i];
  __syncthreads();

  int lr = lane >> 1, hf = lane & 1;
  int grow = bm0 + wid * 32 + lr;
  bool miss = flags[grow] != 0.f;
  float pc[5] = {0, 0, 0, 0, 0};

  for (int tt = 0; tt < 2; ++tt) {
    int t = t0 + tt;
    float itemp = 1.f / tree_temp[t];
    // sigmoid decisions -> LDS
#pragma unroll
    for (int mi = 0; mi < 2; mi++) {
#pragma unroll
      for (int nl = 0; nl < 4; nl++) {
        int node = nl * 16 + m;
        float tb = (node < 63) ? tree_b[t * 63 + node] : 0.f;
        f32x4 a = acc[mi][tt * 4 + nl];
#pragma unroll
        for (int r4 = 0; r4 < 4; r4++) {
          int lrow = mi * 16 + q * 4 + r4;
          float z = (a[r4] + tb) * itemp;
          decw[lrow * 66 + node] = 1.f / (1.f + __expf(-z));
        }
      }
    }
    __syncthreads();
    // routing product + leaf dot; lane = (row pair, class half)
    float a5[5] = {0, 0, 0, 0, 0};
#pragma unroll 4
    for (int l = 0; l < 64; l++) {
      float rt = 1.f;
#pragma unroll
      for (int lvl = 0; lvl < 6; lvl++) {
        int node = (1 << lvl) - 1 + (l & ((1 << lvl) - 1));
        float d = decw[lr * 66 + node];
        d = miss ? 0.5f : d;
        rt *= ((l >> lvl) & 1) ? (1.f - d) : d;
      }
      const float* lv = leaf_s + tt * 640 + l * 10 + hf * 5;
#pragma unroll
      for (int c = 0; c < 5; c++) a5[c] = fmaf(rt, lv[c], a5[c]);
    }
    float w = wbt[grow * 64 + t];
#pragma unroll
    for (int c = 0; c < 5; c++) pc[c] = fmaf(w, a5[c], pc[c]);
    __syncthreads();
  }
#pragma unroll
  for (int c = 0; c < 5; c++) atomicAdd(&pred[grow * 10 + hf * 5 + c], pc[c]);
}

// ---------------- final softmax ----------------
__global__ void k_softmax(const float* __restrict__ pred, float* __restrict__ out) {
  int row = blockIdx.x * 256 + threadIdx.x;
  float v[10];
  float mx = -1e30f;
#pragma unroll
  for (int c = 0; c < 10; c++) {
    v[c] = pred[row * 10 + c];
    mx = fmaxf(mx, v[c]);
  }
  float s = 0.f;
#pragma unroll
  for (int c = 0; c < 10; c++) {
    v[c] = __expf(v[c] - mx);
    s += v[c];
  }
  float inv = 1.f / s;
#pragma unroll
  for (int c = 0; c < 10; c++) out[row * 10 + c] = v[c] * inv;
}

extern "C" void kernel_launch(void* const* d_in, const int* in_sizes, int n_in,
                              void* d_out, int out_size, void* d_ws, size_t ws_size,
                              hipStream_t stream) {
  const float* x    = (const float*)d_in[0];
  const float* w1   = (const float*)d_in[1];
  const float* b1   = (const float*)d_in[2];
  const float* gam  = (const float*)d_in[3];
  const float* bet  = (const float*)d_in[4];
  const float* mu   = (const float*)d_in[5];
  const float* var  = (const float*)d_in[6];
  const float* w2   = (const float*)d_in[7];
  const float* b2   = (const float*)d_in[8];
  const float* tw   = (const float*)d_in[9];
  const float* tb   = (const float*)d_in[10];
  const float* temp = (const float*)d_in[11];
  const float* leaf = (const float*)d_in[12];
  const float* rw   = (const float*)d_in[13];
  float* out = (float*)d_out;

  char* ws = (char*)d_ws;
  unsigned short* xc  = (unsigned short*)(ws);             // 16,777,216 B
  unsigned short* twb = (unsigned short*)(ws + 16777216);  //  4,194,304 B
  unsigned short* w1t = (unsigned short*)(ws + 20971520);  //    131,072 B
  float* h    = (float*)(ws + 21102592);                   //  8,388,608 B
  float* wbt  = (float*)(ws + 29491200);                   //  4,194,304 B
  float* pred = (float*)(ws + 33685504);                   //    655,360 B
  float* flg  = (float*)(ws + 34340864);                   //     65,536 B

  hipMemsetAsync(pred, 0, 16384 * 10 * sizeof(float), stream);
  k_convert_x<<<4096, 256, 0, stream>>>(x, xc, flg);
  k_convert_tw<<<1024, 256, 0, stream>>>(tw, twb);
  k_convert_w1t<<<256, 256, 0, stream>>>(w1, w1t);
  k_attn1<<<256, 256, 0, stream>>>(xc, w1t, b1, gam, bet, mu, var, h);
  k_attn2<<<1024, 256, 0, stream>>>(h, w2, b2, rw, wbt);
  dim3 g2(128, 32);
  k_trees<<<g2, 256, 0, stream>>>(xc, twb, tb, temp, leaf, wbt, flg, pred);
  k_softmax<<<64, 256, 0, stream>>>(pred, out);
}